// Round 1
// baseline (90.844 us; speedup 1.0000x reference)
//
#include <hip/hip_runtime.h>

#define DM 2048
#define BB 64
#define SS 32
#define CC 8
#define KSPLIT 4
#define KRANGE (DM / KSPLIT) // 512

// K1: ut4[(k>>2)*256 + b*4 + (k&3)] = sum_c controls[c][b][k]
// grid 256 (b=64 x kchunk=4), block 128
__global__ void k1_sum_transpose(const float* __restrict__ controls,
                                 float* __restrict__ ut4) {
  const int b  = blockIdx.x >> 2;
  const int k0 = (blockIdx.x & 3) * 512;
  const int k  = k0 + threadIdx.x * 4;
  float4 s = make_float4(0.f, 0.f, 0.f, 0.f);
#pragma unroll
  for (int c = 0; c < CC; ++c) {
    const float4 v = *reinterpret_cast<const float4*>(
        controls + ((size_t)c * BB + b) * DM + k);
    s.x += v.x; s.y += v.y; s.z += v.z; s.w += v.w;
  }
  *reinterpret_cast<float4*>(ut4 + (k >> 2) * 256 + b * 4) = s;
}

// GEMM partial: part[kp][e][b] = sum_{k in kp range} A[b][k] * W[e][k]
// A given interleaved-transposed: a4[(k>>2)*256 + b*4 + (k&3)]
// grid 256 (etile=64 x kp=4), block 256 (4 waves, 8 cols/wave)
__global__ void gemm_partial(const float* __restrict__ a4,
                             const float* __restrict__ w,
                             float* __restrict__ part) {
  const int lane = threadIdx.x & 63;
  const int wv   = __builtin_amdgcn_readfirstlane(threadIdx.x >> 6);
  const int et   = blockIdx.x & 63;
  const int kp   = blockIdx.x >> 6;
  const int e0   = et * 32 + wv * 8;
  const int k0   = kp * KRANGE;

  float acc[8] = {0.f, 0.f, 0.f, 0.f, 0.f, 0.f, 0.f, 0.f};
  const float* ab = a4 + (k0 >> 2) * 256 + lane * 4;
  const float* wb = w + (size_t)e0 * DM + k0;

  for (int kq = 0; kq < KRANGE / 4; ++kq) {
    const float4 a = *reinterpret_cast<const float4*>(ab + kq * 256);
#pragma unroll
    for (int j = 0; j < 8; ++j) {
      const float4 ww = *reinterpret_cast<const float4*>(
          wb + (size_t)j * DM + kq * 4);
      acc[j] += a.x * ww.x + a.y * ww.y + a.z * ww.z + a.w * ww.w;
    }
  }
#pragma unroll
  for (int j = 0; j < 8; ++j)
    part[((size_t)kp * DM + e0 + j) * 64 + lane] = acc[j];
}

// R1: reduce partials + C*bias, write in interleaved-transposed A4 layout
// out4[(e>>2)*256 + b*4 + (e&3)] = sum_kp part[kp][e][b] + 8*bias[e]
// grid 128, block 256
__global__ void reduce_to_a4(const float* __restrict__ part,
                             const float* __restrict__ bias,
                             float* __restrict__ out4) {
  const int idx = blockIdx.x * 256 + threadIdx.x; // 32768
  const int b  = idx & 63;
  const int eq = idx >> 6; // 0..511
  float s[4];
#pragma unroll
  for (int i = 0; i < 4; ++i) {
    const int e = eq * 4 + i;
    float v = 8.0f * bias[e];
#pragma unroll
    for (int kp = 0; kp < KSPLIT; ++kp)
      v += part[((size_t)kp * DM + e) * 64 + b];
    s[i] = v;
  }
  *reinterpret_cast<float4*>(out4 + eq * 256 + b * 4) =
      make_float4(s[0], s[1], s[2], s[3]);
}

// R2: pt[o*64 + b] = sum_kp part[kp][o][b] + 8*bias[o]
// grid 512, block 256
__global__ void reduce_to_pt(const float* __restrict__ part,
                             const float* __restrict__ bias,
                             float* __restrict__ pt) {
  const int idx = blockIdx.x * 256 + threadIdx.x; // 131072
  const int b = idx & 63;
  const int o = idx >> 6;
  float v = 8.0f * bias[o];
#pragma unroll
  for (int kp = 0; kp < KSPLIT; ++kp)
    v += part[((size_t)kp * DM + o) * 64 + b];
  pt[idx] = v;
}

// K4: out[b][s][e] = seq[b][s][e] + pt[e*64+b]
// grid 256 (b=64 x ehalf=2 x shalf=2), block 256
__global__ void k4_broadcast_add(const float* __restrict__ seq,
                                 const float* __restrict__ pt,
                                 float* __restrict__ out) {
  __shared__ float p[1024];
  const int bi = blockIdx.x;
  const int b  = bi >> 2;
  const int e0 = ((bi >> 1) & 1) * 1024;
  const int s0 = (bi & 1) * 16;
  const int t  = threadIdx.x;
  for (int i = t; i < 1024; i += 256)
    p[i] = pt[(size_t)(e0 + i) * 64 + b];
  __syncthreads();
  const float4 pv = *reinterpret_cast<const float4*>(&p[t * 4]);
  const size_t base = (size_t)b * SS * DM + e0 + t * 4;
  for (int s = s0; s < s0 + 16; ++s) {
    const float4 q =
        *reinterpret_cast<const float4*>(seq + base + (size_t)s * DM);
    *reinterpret_cast<float4*>(out + base + (size_t)s * DM) =
        make_float4(q.x + pv.x, q.y + pv.y, q.z + pv.z, q.w + pv.w);
  }
}

extern "C" void kernel_launch(void* const* d_in, const int* in_sizes, int n_in,
                              void* d_out, int out_size, void* d_ws,
                              size_t ws_size, hipStream_t stream) {
  const float* seq      = (const float*)d_in[0];
  const float* controls = (const float*)d_in[1];
  // d_in[2..5] = Wq, bq, Wk, bk — mathematically unused (softmax over size-1 axis == 1)
  const float* Wv = (const float*)d_in[6];
  const float* bv = (const float*)d_in[7];
  const float* Wo = (const float*)d_in[8];
  const float* bo = (const float*)d_in[9];
  float* out = (float*)d_out;

  char* ws = (char*)d_ws;
  float* ut4 = (float*)(ws);                      // 512 KB  [512][64][4]
  float* pV  = (float*)(ws + (512ull << 10));     // 2 MB    [4][2048][64]
  float* vt4 = (float*)(ws + (2560ull << 10));    // 512 KB
  float* pP  = (float*)(ws + (3072ull << 10));    // 2 MB
  float* pt  = (float*)(ws + (5120ull << 10));    // 512 KB  [2048][64]

  k1_sum_transpose<<<256, 128, 0, stream>>>(controls, ut4);
  gemm_partial<<<256, 256, 0, stream>>>(ut4, Wv, pV);
  reduce_to_a4<<<128, 256, 0, stream>>>(pV, bv, vt4);
  gemm_partial<<<256, 256, 0, stream>>>(vt4, Wo, pP);
  reduce_to_pt<<<512, 256, 0, stream>>>(pP, bo, pt);
  k4_broadcast_add<<<256, 256, 0, stream>>>(seq, pt, out);
}